// Round 8
// baseline (754.691 us; speedup 1.0000x reference)
//
#include <hip/hip_runtime.h>

#define NNODES 50000
#define HID 128
#define NREL 9
#define NLAYERS 3
#define NEDGES 600000

#define NBINS (NREL * NNODES)          // 450000, binned [dest][rel]: bin = d*9+r
#define SCAN_CHUNK 1024
#define NBLK ((NBINS + SCAN_CHUNK - 1) / SCAN_CHUNK)   // 440

#define GM 64                           // GEMM M-tile
#define KTOT (NREL * HID)               // 1152

typedef __attribute__((ext_vector_type(8))) short short8;
typedef __attribute__((ext_vector_type(4))) float f32x4;

__device__ __forceinline__ short f2bf(float f) {
    union { float f; unsigned u; } c; c.f = f;
    unsigned r = c.u + 0x7fff + ((c.u >> 16) & 1);   // RNE
    return (short)(r >> 16);
}
__device__ __forceinline__ float bf2f(short v) {
    return __uint_as_float(((unsigned)(unsigned short)v) << 16);
}

// ---------------- CSR build: counting sort by (dest, rel) ----------------

__global__ void hist2_kernel(const int* __restrict__ dst, const int* __restrict__ etype,
                             int* __restrict__ bins) {
    int e = blockIdx.x * blockDim.x + threadIdx.x;
    if (e < NEDGES) {
        int bin = dst[e] * NREL + etype[e];
        atomicAdd(&bins[bin], 1);
    }
}

__global__ __launch_bounds__(256) void scan_pass1(const int* __restrict__ bins,
                                                  int* __restrict__ blocksum) {
    __shared__ int red[256];
    int b = blockIdx.x, t = threadIdx.x;
    int i0 = b * SCAN_CHUNK + t * 4;
    int s = 0;
#pragma unroll
    for (int k = 0; k < 4; k++)
        if (i0 + k < NBINS) s += bins[i0 + k];
    red[t] = s;
    __syncthreads();
    for (int off = 128; off > 0; off >>= 1) {
        if (t < off) red[t] += red[t + off];
        __syncthreads();
    }
    if (t == 0) blocksum[b] = red[0];
}

__global__ __launch_bounds__(512) void scan_pass2(const int* __restrict__ blocksum,
                                                  int* __restrict__ blockoff,
                                                  int* __restrict__ rowptr) {
    __shared__ int s[512];
    int t = threadIdx.x;
    int v = (t < NBLK) ? blocksum[t] : 0;
    s[t] = v;
    __syncthreads();
    for (int off = 1; off < 512; off <<= 1) {
        int x = (t >= off) ? s[t - off] : 0;
        __syncthreads();
        s[t] += x;
        __syncthreads();
    }
    if (t < NBLK) blockoff[t] = s[t] - v;
    if (t == 0) rowptr[NBINS] = NEDGES;
}

__global__ __launch_bounds__(256) void scan_pass3(const int* __restrict__ bins,
                                                  const int* __restrict__ blockoff,
                                                  int* __restrict__ rowptr,
                                                  int* __restrict__ cursor) {
    __shared__ int sc[256];
    int b = blockIdx.x, t = threadIdx.x;
    int i0 = b * SCAN_CHUNK + t * 4;
    int v[4], p[4];
    int s = 0;
#pragma unroll
    for (int k = 0; k < 4; k++) {
        v[k] = (i0 + k < NBINS) ? bins[i0 + k] : 0;
        p[k] = s;
        s += v[k];
    }
    sc[t] = s;
    __syncthreads();
    for (int off = 1; off < 256; off <<= 1) {
        int x = (t >= off) ? sc[t - off] : 0;
        __syncthreads();
        sc[t] += x;
        __syncthreads();
    }
    int base = blockoff[b] + (sc[t] - s);
#pragma unroll
    for (int k = 0; k < 4; k++) {
        if (i0 + k < NBINS) {
            rowptr[i0 + k] = base + p[k];
            cursor[i0 + k] = base + p[k];
        }
    }
}

__global__ void place_kernel(const int* __restrict__ dst, const int* __restrict__ src,
                             const int* __restrict__ etype,
                             int* __restrict__ cursor, int* __restrict__ bsrc) {
    int e = blockIdx.x * blockDim.x + threadIdx.x;
    if (e < NEDGES) {
        int bin = dst[e] * NREL + etype[e];
        int pos = atomicAdd(&cursor[bin], 1);
        bsrc[pos] = src[e];
    }
}

// ---------------- converts ----------------
// Wt2[l][n][r*128+i] = bf16(W[l][r][i][n]);  one block per (l,r)

__global__ __launch_bounds__(256) void convert_w(const float* __restrict__ W,
                                                 short* __restrict__ Wt2) {
    int lr = blockIdx.x;
    int l = lr / NREL, r = lr - l * NREL;
    const float* w = W + (size_t)lr * HID * HID;
    short* o = Wt2 + (size_t)l * HID * KTOT;
    int tid = threadIdx.x;
#pragma unroll 4
    for (int i = 0; i < 64; i++) {
        int elem = i * 256 + tid;
        int kk = elem >> 7, n = elem & 127;
        o[(size_t)n * KTOT + r * HID + kk] = f2bf(w[elem]);
    }
}

// emb fp32 -> bf16

__global__ __launch_bounds__(256) void convert_emb(const float* __restrict__ E,
                                                   short* __restrict__ Ebf) {
    int gid = blockIdx.x * blockDim.x + threadIdx.x;
    const float* p = E + (size_t)gid * 8;
    float4 v0 = *(const float4*)p;
    float4 v1 = *(const float4*)(p + 4);
    short8 o = {f2bf(v0.x), f2bf(v0.y), f2bf(v0.z), f2bf(v0.w),
                f2bf(v1.x), f2bf(v1.y), f2bf(v1.z), f2bf(v1.w)};
    *(short8*)(Ebf + (size_t)gid * 8) = o;
}

// ---------------- gather: S[bin][0..127] = sum_{e in CSR(bin)} Hbf[src_e] ----------------
// thread = (bin, 8-col chunk); 7.2M threads, no barriers, no chains beyond bin degree.

__global__ __launch_bounds__(256) void gather_kernel(const short* __restrict__ Hbf,
                                                     const int* __restrict__ bsrc,
                                                     const int* __restrict__ rowptr,
                                                     short* __restrict__ S) {
    int gid = blockIdx.x * blockDim.x + threadIdx.x;
    int bin = gid >> 4;
    int ck  = gid & 15;           // 8 cols each
    int rs = rowptr[bin];
    int re = rowptr[bin + 1];
    float a[8];
#pragma unroll
    for (int i = 0; i < 8; i++) a[i] = 0.f;
    for (int j = rs; j < re; j++) {
        int s = bsrc[j];
        short8 v = *(const short8*)(Hbf + (size_t)s * HID + ck * 8);
#pragma unroll
        for (int i = 0; i < 8; i++) a[i] += bf2f(v[i]);
    }
    short8 o = {f2bf(a[0]), f2bf(a[1]), f2bf(a[2]), f2bf(a[3]),
                f2bf(a[4]), f2bf(a[5]), f2bf(a[6]), f2bf(a[7])};
    *(short8*)(S + (size_t)bin * HID + ck * 8) = o;
}

// ---------------- gemm: Hout[d][n] = act( sum_k S[d][k] Wt2[n][k] + sum_r cnt*bias ) ----------------
// A = S [50000 x 1152] bf16 row-major (streamed from global, no LDS staging),
// B = Wt2 [128 n x 1152 k] bf16 (L2-resident). 36 k-steps x 8 MFMA per wave.

__global__ __launch_bounds__(256) void gemm_kernel(const short* __restrict__ S,
                                                   const short* __restrict__ Wt2l,
                                                   const float* __restrict__ Bias, // [9][128]
                                                   const int* __restrict__ rowptr,
                                                   short* __restrict__ HoutBf,     // if !last: bf16+relu
                                                   float* __restrict__ HoutF,      // if last: fp32
                                                   int last) {
    __shared__ int   rp_s[GM * NREL + 1];       // 577 ints
    __shared__ float bias_s[NREL * HID];        // 1152 floats

    int tid  = threadIdx.x;
    int wave = tid >> 6, lane = tid & 63;
    int row0 = blockIdx.x * GM;
    int m0   = wave * 16;
    int lm = lane & 15, lq = lane >> 4;

    int rpbase = row0 * NREL;
    for (int i = tid; i <= GM * NREL; i += 256) {
        int g = rpbase + i;
        rp_s[i] = rowptr[(g < NBINS) ? g : NBINS];
    }
    for (int i = tid; i < NREL * HID; i += 256) bias_s[i] = Bias[i];
    __syncthreads();

    int arow = row0 + m0 + lm;
    if (arow > NNODES - 1) arow = NNODES - 1;   // clamp (stores guarded)
    const short* Ap = S + (size_t)arow * KTOT + lq * 8;

    f32x4 acc[8];
#pragma unroll
    for (int nt = 0; nt < 8; nt++) acc[nt] = (f32x4){0.f, 0.f, 0.f, 0.f};

    for (int kc = 0; kc < KTOT / 32; kc++) {
        short8 af = *(const short8*)(Ap + kc * 32);
        const short* Bp = Wt2l + (size_t)lm * KTOT + kc * 32 + lq * 8;
#pragma unroll
        for (int nt = 0; nt < 8; nt++) {
            short8 bf = *(const short8*)(Bp + (size_t)nt * 16 * KTOT);
            acc[nt] = __builtin_amdgcn_mfma_f32_16x16x32_bf16(af, bf, acc[nt], 0, 0, 0);
        }
    }

    // epilogue. C/D layout: col = lane&15 (n sub), row = lq*4 + reg
#pragma unroll
    for (int reg = 0; reg < 4; reg++) {
        int rl = m0 + lq * 4 + reg;
        int d  = row0 + rl;
        if (d >= NNODES) continue;
        float cr[NREL];
#pragma unroll
        for (int r = 0; r < NREL; r++)
            cr[r] = (float)(rp_s[rl * NREL + r + 1] - rp_s[rl * NREL + r]);
#pragma unroll
        for (int nt = 0; nt < 8; nt++) {
            int n = nt * 16 + lm;
            float b = 0.f;
#pragma unroll
            for (int r = 0; r < NREL; r++) b += cr[r] * bias_s[r * HID + n];
            float o = acc[nt][reg] + b;
            if (!last) {
                o = fmaxf(o, 0.f);
                HoutBf[(size_t)d * HID + n] = f2bf(o);
            } else {
                HoutF[(size_t)d * HID + n] = o;
            }
        }
    }
}

// ---------------- driver ----------------

extern "C" void kernel_launch(void* const* d_in, const int* in_sizes, int n_in,
                              void* d_out, int out_size, void* d_ws, size_t ws_size,
                              hipStream_t stream) {
    const int*   edge_index = (const int*)d_in[0];   // [2, NEDGES]: row0=dest, row1=src
    const int*   etype      = (const int*)d_in[1];
    const float* emb        = (const float*)d_in[2];
    const float* W          = (const float*)d_in[3]; // [3,9,128,128]
    const float* Bias       = (const float*)d_in[4]; // [3,9,128]
    float*       out        = (float*)d_out;

    const int* dst  = edge_index;
    const int* srcA = edge_index + NEDGES;

    // ws layout (shorts/ints)
    short* Ebf = (short*)d_ws;                              // 50000*128 bf16
    short* Hbf = Ebf + (size_t)NNODES * HID;                // 50000*128 bf16
    short* S   = Hbf + (size_t)NNODES * HID;                // 50000*1152 bf16 (115.2 MB)
    short* Wt2 = S + (size_t)NNODES * KTOT;                 // 3*128*1152 bf16
    int*   bsrc     = (int*)(Wt2 + (size_t)NLAYERS * HID * KTOT);
    int*   bins     = bsrc + NEDGES;
    int*   cursor   = bins + NBINS;
    int*   rowptr   = cursor + NBINS;                       // NBINS+1
    int*   blocksum = rowptr + NBINS + 1;
    int*   blockoff = blocksum + NBLK;

    hipMemsetAsync(bins, 0, NBINS * sizeof(int), stream);
    hist2_kernel<<<(NEDGES + 255) / 256, 256, 0, stream>>>(dst, etype, bins);
    scan_pass1<<<NBLK, 256, 0, stream>>>(bins, blocksum);
    scan_pass2<<<1, 512, 0, stream>>>(blocksum, blockoff, rowptr);
    scan_pass3<<<NBLK, 256, 0, stream>>>(bins, blockoff, rowptr, cursor);
    place_kernel<<<(NEDGES + 255) / 256, 256, 0, stream>>>(dst, srcA, etype, cursor, bsrc);
    convert_w<<<NLAYERS * NREL, 256, 0, stream>>>(W, Wt2);
    convert_emb<<<(NNODES * HID / 8) / 256, 256, 0, stream>>>(emb, Ebf);

    const short* Hin = Ebf;
    for (int l = 0; l < NLAYERS; l++) {
        gather_kernel<<<(NBINS * 16) / 256, 256, 0, stream>>>(Hin, bsrc, rowptr, S);
        const short* Wtl = Wt2 + (size_t)l * HID * KTOT;
        const float* Bl  = Bias + (size_t)l * NREL * HID;
        int last = (l + 1 == NLAYERS);
        gemm_kernel<<<(NNODES + GM - 1) / GM, 256, 0, stream>>>(
            S, Wtl, Bl, rowptr, Hbf, out, last);
        Hin = Hbf;
    }
}

// Round 9
// 515.113 us; speedup vs baseline: 1.4651x; 1.4651x over previous
//
#include <hip/hip_runtime.h>

#define NNODES 50000
#define HID 128
#define NREL 9
#define NLAYERS 3
#define NEDGES 600000

#define NBINS (NREL * NNODES)          // 450000, bin = d*9+r
#define SCAN_CHUNK 1024
#define NBLK ((NBINS + SCAN_CHUNK - 1) / SCAN_CHUNK)   // 440

#define KTOT (NREL * HID)               // 1152
#define GM2 128                         // GEMM M-tile
#define BK 64                           // K-chunk
#define PITCH 72                        // LDS pitch (shorts): 144 B rows -> 2-way banks (free)
#define EPITCH 136                      // epilogue LDS pitch

typedef __attribute__((ext_vector_type(8))) short short8;
typedef __attribute__((ext_vector_type(4))) float f32x4;

__device__ __forceinline__ short f2bf(float f) {
    union { float f; unsigned u; } c; c.f = f;
    unsigned r = c.u + 0x7fff + ((c.u >> 16) & 1);   // RNE
    return (short)(r >> 16);
}
__device__ __forceinline__ float bf2f(short v) {
    return __uint_as_float(((unsigned)(unsigned short)v) << 16);
}

// ---------------- CSR build: counting sort by (dest, rel) ----------------

__global__ void hist2_kernel(const int* __restrict__ dst, const int* __restrict__ etype,
                             int* __restrict__ bins) {
    int e = blockIdx.x * blockDim.x + threadIdx.x;
    if (e < NEDGES) {
        int bin = dst[e] * NREL + etype[e];
        atomicAdd(&bins[bin], 1);
    }
}

__global__ __launch_bounds__(256) void scan_pass1(const int* __restrict__ bins,
                                                  int* __restrict__ blocksum) {
    __shared__ int red[256];
    int b = blockIdx.x, t = threadIdx.x;
    int i0 = b * SCAN_CHUNK + t * 4;
    int s = 0;
#pragma unroll
    for (int k = 0; k < 4; k++)
        if (i0 + k < NBINS) s += bins[i0 + k];
    red[t] = s;
    __syncthreads();
    for (int off = 128; off > 0; off >>= 1) {
        if (t < off) red[t] += red[t + off];
        __syncthreads();
    }
    if (t == 0) blocksum[b] = red[0];
}

__global__ __launch_bounds__(512) void scan_pass2(const int* __restrict__ blocksum,
                                                  int* __restrict__ blockoff,
                                                  int* __restrict__ rowptr) {
    __shared__ int s[512];
    int t = threadIdx.x;
    int v = (t < NBLK) ? blocksum[t] : 0;
    s[t] = v;
    __syncthreads();
    for (int off = 1; off < 512; off <<= 1) {
        int x = (t >= off) ? s[t - off] : 0;
        __syncthreads();
        s[t] += x;
        __syncthreads();
    }
    if (t < NBLK) blockoff[t] = s[t] - v;
    if (t == 0) rowptr[NBINS] = NEDGES;
}

__global__ __launch_bounds__(256) void scan_pass3(const int* __restrict__ bins,
                                                  const int* __restrict__ blockoff,
                                                  int* __restrict__ rowptr,
                                                  int* __restrict__ cursor) {
    __shared__ int sc[256];
    int b = blockIdx.x, t = threadIdx.x;
    int i0 = b * SCAN_CHUNK + t * 4;
    int v[4], p[4];
    int s = 0;
#pragma unroll
    for (int k = 0; k < 4; k++) {
        v[k] = (i0 + k < NBINS) ? bins[i0 + k] : 0;
        p[k] = s;
        s += v[k];
    }
    sc[t] = s;
    __syncthreads();
    for (int off = 1; off < 256; off <<= 1) {
        int x = (t >= off) ? sc[t - off] : 0;
        __syncthreads();
        sc[t] += x;
        __syncthreads();
    }
    int base = blockoff[b] + (sc[t] - s);
#pragma unroll
    for (int k = 0; k < 4; k++) {
        if (i0 + k < NBINS) {
            rowptr[i0 + k] = base + p[k];
            cursor[i0 + k] = base + p[k];
        }
    }
}

__global__ void place_kernel(const int* __restrict__ dst, const int* __restrict__ src,
                             const int* __restrict__ etype,
                             int* __restrict__ cursor, int* __restrict__ bsrc) {
    int e = blockIdx.x * blockDim.x + threadIdx.x;
    if (e < NEDGES) {
        int bin = dst[e] * NREL + etype[e];
        int pos = atomicAdd(&cursor[bin], 1);
        bsrc[pos] = src[e];
    }
}

// ---------------- converts ----------------
// Wt2[l][n][r*128+i] = bf16(W[l][r][i][n])

__global__ __launch_bounds__(256) void convert_w(const float* __restrict__ W,
                                                 short* __restrict__ Wt2) {
    int lr = blockIdx.x;
    int l = lr / NREL, r = lr - l * NREL;
    const float* w = W + (size_t)lr * HID * HID;
    short* o = Wt2 + (size_t)l * HID * KTOT;
    int tid = threadIdx.x;
#pragma unroll 4
    for (int i = 0; i < 64; i++) {
        int elem = i * 256 + tid;
        int kk = elem >> 7, n = elem & 127;
        o[(size_t)n * KTOT + r * HID + kk] = f2bf(w[elem]);
    }
}

__global__ __launch_bounds__(256) void convert_emb(const float* __restrict__ E,
                                                   short* __restrict__ Ebf) {
    int gid = blockIdx.x * blockDim.x + threadIdx.x;
    const float* p = E + (size_t)gid * 8;
    float4 v0 = *(const float4*)p;
    float4 v1 = *(const float4*)(p + 4);
    short8 o = {f2bf(v0.x), f2bf(v0.y), f2bf(v0.z), f2bf(v0.w),
                f2bf(v1.x), f2bf(v1.y), f2bf(v1.z), f2bf(v1.w)};
    *(short8*)(Ebf + (size_t)gid * 8) = o;
}

// ---------------- gather: S[bin][0..127] = sum_{e in CSR(bin)} Hbf[src_e] ----------------
// thread = (bin, 16-col chunk); 3.6M threads, barrier-free, coalesced writes.

__global__ __launch_bounds__(256) void gather_kernel(const short* __restrict__ Hbf,
                                                     const int* __restrict__ bsrc,
                                                     const int* __restrict__ rowptr,
                                                     short* __restrict__ S) {
    int gid = blockIdx.x * blockDim.x + threadIdx.x;
    int bin = gid >> 3;
    if (bin >= NBINS) return;
    int ck  = gid & 7;            // 16 cols each
    int rs = rowptr[bin];
    int re = rowptr[bin + 1];
    float a[16];
#pragma unroll
    for (int i = 0; i < 16; i++) a[i] = 0.f;
    for (int j = rs; j < re; j++) {
        int s = bsrc[j];
        const short* hp = Hbf + (size_t)s * HID + ck * 16;
        short8 v0 = *(const short8*)hp;
        short8 v1 = *(const short8*)(hp + 8);
#pragma unroll
        for (int i = 0; i < 8; i++) a[i]     += bf2f(v0[i]);
#pragma unroll
        for (int i = 0; i < 8; i++) a[i + 8] += bf2f(v1[i]);
    }
    short8 o0 = {f2bf(a[0]),  f2bf(a[1]),  f2bf(a[2]),  f2bf(a[3]),
                 f2bf(a[4]),  f2bf(a[5]),  f2bf(a[6]),  f2bf(a[7])};
    short8 o1 = {f2bf(a[8]),  f2bf(a[9]),  f2bf(a[10]), f2bf(a[11]),
                 f2bf(a[12]), f2bf(a[13]), f2bf(a[14]), f2bf(a[15])};
    short* sp = S + (size_t)bin * HID + ck * 16;
    *(short8*)sp       = o0;
    *(short8*)(sp + 8) = o1;
}

// ---------------- gemm: Hout[d][n] = act( sum_k S[d][k] Wt2[n][k] + sum_r cnt*bias ) ----------------
// Tiled: 128-row M-tile, K=1152 in 18 chunks of 64, LDS-staged A/B, ds_read_b128
// fragments, coalesced bf16 epilogue via LDS transpose.

__global__ __launch_bounds__(256) void gemm_kernel(const short* __restrict__ S,
                                                   const short* __restrict__ Wt2l,
                                                   const float* __restrict__ Bias, // [9][128]
                                                   const int* __restrict__ rowptr,
                                                   short* __restrict__ HoutBf,     // !last: bf16+relu
                                                   float* __restrict__ HoutF,      // last: fp32
                                                   int last) {
    __shared__ short lds[2 * GM2 * PITCH];      // As | Bs; reused as Et[128][EPITCH]
    __shared__ int   rp_s[GM2 * NREL + 1];
    __shared__ float bias_s[NREL * HID];
    short* As = lds;
    short* Bs = lds + GM2 * PITCH;

    int tid  = threadIdx.x;
    int wave = tid >> 6, lane = tid & 63;
    int row0 = blockIdx.x * GM2;
    int m0   = wave * 32;
    int lm = lane & 15, lq = lane >> 4;

    int rpbase = row0 * NREL;
    for (int i = tid; i <= GM2 * NREL; i += 256) {
        int g = rpbase + i;
        rp_s[i] = rowptr[(g < NBINS) ? g : NBINS];
    }
    for (int i = tid; i < NREL * HID; i += 256) bias_s[i] = Bias[i];

    f32x4 acc[2][8];
#pragma unroll
    for (int mf = 0; mf < 2; mf++)
#pragma unroll
        for (int nt = 0; nt < 8; nt++) acc[mf][nt] = (f32x4){0.f, 0.f, 0.f, 0.f};

    for (int kc = 0; kc < KTOT / BK; kc++) {    // 18 chunks
        __syncthreads();
        // stage A (S rows) and B (Wt2 rows): 128 rows x 64 cols each
#pragma unroll
        for (int i = 0; i < 4; i++) {
            int p = i * 256 + tid;
            int row = p >> 3, ck = p & 7;
            short8 va = *(const short8*)(S + (size_t)(row0 + row) * KTOT + kc * BK + ck * 8);
            *(short8*)&As[row * PITCH + ck * 8] = va;
            short8 vb = *(const short8*)(Wt2l + (size_t)row * KTOT + kc * BK + ck * 8);
            *(short8*)&Bs[row * PITCH + ck * 8] = vb;
        }
        __syncthreads();
#pragma unroll
        for (int ks = 0; ks < 2; ks++) {
            short8 af0 = *(const short8*)&As[(m0 + lm) * PITCH + ks * 32 + lq * 8];
            short8 af1 = *(const short8*)&As[(m0 + 16 + lm) * PITCH + ks * 32 + lq * 8];
#pragma unroll
            for (int nt = 0; nt < 8; nt++) {
                short8 bf = *(const short8*)&Bs[(nt * 16 + lm) * PITCH + ks * 32 + lq * 8];
                acc[0][nt] = __builtin_amdgcn_mfma_f32_16x16x32_bf16(af0, bf, acc[0][nt], 0, 0, 0);
                acc[1][nt] = __builtin_amdgcn_mfma_f32_16x16x32_bf16(af1, bf, acc[1][nt], 0, 0, 0);
            }
        }
    }
    __syncthreads();   // As/Bs reads done; safe to reuse lds as Et

    // epilogue. C/D layout: col = nt*16+lm, row(in frag) = lq*4+reg
    if (!last) {
        short (*Et)[EPITCH] = (short(*)[EPITCH])lds;
#pragma unroll
        for (int mf = 0; mf < 2; mf++) {
#pragma unroll
            for (int reg = 0; reg < 4; reg++) {
                int rl = m0 + mf * 16 + lq * 4 + reg;
                float cr[NREL];
#pragma unroll
                for (int r = 0; r < NREL; r++)
                    cr[r] = (float)(rp_s[rl * NREL + r + 1] - rp_s[rl * NREL + r]);
#pragma unroll
                for (int nt = 0; nt < 8; nt++) {
                    int n = nt * 16 + lm;
                    float b = 0.f;
#pragma unroll
                    for (int r = 0; r < NREL; r++) b += cr[r] * bias_s[r * HID + n];
                    float o = fmaxf(acc[mf][nt][reg] + b, 0.f);
                    Et[rl][n] = f2bf(o);
                }
            }
        }
        __syncthreads();
#pragma unroll
        for (int i = 0; i < 8; i++) {
            int p = i * 256 + tid;
            int row = p >> 4, ck = p & 15;
            int d = row0 + row;
            if (d < NNODES)
                *(short8*)(HoutBf + (size_t)d * HID + ck * 8) = *(const short8*)&Et[row][ck * 8];
        }
    } else {
#pragma unroll
        for (int mf = 0; mf < 2; mf++) {
#pragma unroll
            for (int reg = 0; reg < 4; reg++) {
                int rl = m0 + mf * 16 + lq * 4 + reg;
                int d  = row0 + rl;
                if (d >= NNODES) continue;
                float cr[NREL];
#pragma unroll
                for (int r = 0; r < NREL; r++)
                    cr[r] = (float)(rp_s[rl * NREL + r + 1] - rp_s[rl * NREL + r]);
#pragma unroll
                for (int nt = 0; nt < 8; nt++) {
                    int n = nt * 16 + lm;
                    float b = 0.f;
#pragma unroll
                    for (int r = 0; r < NREL; r++) b += cr[r] * bias_s[r * HID + n];
                    HoutF[(size_t)d * HID + n] = acc[mf][nt][reg] + b;
                }
            }
        }
    }
}

// ---------------- driver ----------------

extern "C" void kernel_launch(void* const* d_in, const int* in_sizes, int n_in,
                              void* d_out, int out_size, void* d_ws, size_t ws_size,
                              hipStream_t stream) {
    const int*   edge_index = (const int*)d_in[0];   // [2, NEDGES]: row0=dest, row1=src
    const int*   etype      = (const int*)d_in[1];
    const float* emb        = (const float*)d_in[2];
    const float* W          = (const float*)d_in[3]; // [3,9,128,128]
    const float* Bias       = (const float*)d_in[4]; // [3,9,128]
    float*       out        = (float*)d_out;

    const int* dst  = edge_index;
    const int* srcA = edge_index + NEDGES;

    // ws layout
    short* Ebf = (short*)d_ws;                              // 50000*128 bf16
    short* Hbf = Ebf + (size_t)NNODES * HID;                // 50000*128 bf16
    short* S   = Hbf + (size_t)NNODES * HID;                // 50000*1152 bf16 (115.2 MB)
    short* Wt2 = S + (size_t)NNODES * KTOT;                 // 3*128*1152 bf16
    int*   bsrc     = (int*)(Wt2 + (size_t)NLAYERS * HID * KTOT);
    int*   bins     = bsrc + NEDGES;
    int*   cursor   = bins + NBINS;
    int*   rowptr   = cursor + NBINS;                       // NBINS+1
    int*   blocksum = rowptr + NBINS + 1;
    int*   blockoff = blocksum + NBLK;

    hipMemsetAsync(bins, 0, NBINS * sizeof(int), stream);
    hist2_kernel<<<(NEDGES + 255) / 256, 256, 0, stream>>>(dst, etype, bins);
    scan_pass1<<<NBLK, 256, 0, stream>>>(bins, blocksum);
    scan_pass2<<<1, 512, 0, stream>>>(blocksum, blockoff, rowptr);
    scan_pass3<<<NBLK, 256, 0, stream>>>(bins, blockoff, rowptr, cursor);
    place_kernel<<<(NEDGES + 255) / 256, 256, 0, stream>>>(dst, srcA, etype, cursor, bsrc);
    convert_w<<<NLAYERS * NREL, 256, 0, stream>>>(W, Wt2);
    convert_emb<<<(NNODES * HID / 8) / 256, 256, 0, stream>>>(emb, Ebf);

    const short* Hin = Ebf;
    for (int l = 0; l < NLAYERS; l++) {
        gather_kernel<<<(NBINS * 8 + 255) / 256, 256, 0, stream>>>(Hin, bsrc, rowptr, S);
        const short* Wtl = Wt2 + (size_t)l * HID * KTOT;
        const float* Bl  = Bias + (size_t)l * NREL * HID;
        int last = (l + 1 == NLAYERS);
        gemm_kernel<<<(NNODES + GM2 - 1) / GM2, 256, 0, stream>>>(
            S, Wtl, Bl, rowptr, Hbf, out, last);
        Hin = Hbf;
    }
}

// Round 10
// 441.180 us; speedup vs baseline: 1.7106x; 1.1676x over previous
//
#include <hip/hip_runtime.h>

#define NNODES 50000
#define HID 128
#define NREL 9
#define NLAYERS 3
#define NEDGES 600000

#define NBINS (NREL * NNODES)          // 450000, bin = d*9+r
#define SCAN_CHUNK 1024
#define NBLK ((NBINS + SCAN_CHUNK - 1) / SCAN_CHUNK)   // 440

#define KTOT (NREL * HID)               // 1152
#define GM2 64                          // GEMM M-tile
#define BK 64                           // K-chunk
#define NCHUNK (KTOT / BK)              // 18
#define PITCH 72                        // LDS pitch (shorts): 144 B rows -> 2-way banks (free)
#define EPITCH 136                      // epilogue LDS pitch

typedef __attribute__((ext_vector_type(8))) short short8;
typedef __attribute__((ext_vector_type(4))) float f32x4;

__device__ __forceinline__ short f2bf(float f) {
    union { float f; unsigned u; } c; c.f = f;
    unsigned r = c.u + 0x7fff + ((c.u >> 16) & 1);   // RNE
    return (short)(r >> 16);
}
__device__ __forceinline__ float bf2f(short v) {
    return __uint_as_float(((unsigned)(unsigned short)v) << 16);
}

// ---------------- CSR build: counting sort by (dest, rel) ----------------

__global__ void hist2_kernel(const int* __restrict__ dst, const int* __restrict__ etype,
                             int* __restrict__ bins) {
    int e = blockIdx.x * blockDim.x + threadIdx.x;
    if (e < NEDGES) {
        int bin = dst[e] * NREL + etype[e];
        atomicAdd(&bins[bin], 1);
    }
}

__global__ __launch_bounds__(256) void scan_pass1(const int* __restrict__ bins,
                                                  int* __restrict__ blocksum) {
    __shared__ int red[256];
    int b = blockIdx.x, t = threadIdx.x;
    int i0 = b * SCAN_CHUNK + t * 4;
    int s = 0;
#pragma unroll
    for (int k = 0; k < 4; k++)
        if (i0 + k < NBINS) s += bins[i0 + k];
    red[t] = s;
    __syncthreads();
    for (int off = 128; off > 0; off >>= 1) {
        if (t < off) red[t] += red[t + off];
        __syncthreads();
    }
    if (t == 0) blocksum[b] = red[0];
}

__global__ __launch_bounds__(512) void scan_pass2(const int* __restrict__ blocksum,
                                                  int* __restrict__ blockoff,
                                                  int* __restrict__ rowptr) {
    __shared__ int s[512];
    int t = threadIdx.x;
    int v = (t < NBLK) ? blocksum[t] : 0;
    s[t] = v;
    __syncthreads();
    for (int off = 1; off < 512; off <<= 1) {
        int x = (t >= off) ? s[t - off] : 0;
        __syncthreads();
        s[t] += x;
        __syncthreads();
    }
    if (t < NBLK) blockoff[t] = s[t] - v;
    if (t == 0) rowptr[NBINS] = NEDGES;
}

__global__ __launch_bounds__(256) void scan_pass3(const int* __restrict__ bins,
                                                  const int* __restrict__ blockoff,
                                                  int* __restrict__ rowptr,
                                                  int* __restrict__ cursor) {
    __shared__ int sc[256];
    int b = blockIdx.x, t = threadIdx.x;
    int i0 = b * SCAN_CHUNK + t * 4;
    int v[4], p[4];
    int s = 0;
#pragma unroll
    for (int k = 0; k < 4; k++) {
        v[k] = (i0 + k < NBINS) ? bins[i0 + k] : 0;
        p[k] = s;
        s += v[k];
    }
    sc[t] = s;
    __syncthreads();
    for (int off = 1; off < 256; off <<= 1) {
        int x = (t >= off) ? sc[t - off] : 0;
        __syncthreads();
        sc[t] += x;
        __syncthreads();
    }
    int base = blockoff[b] + (sc[t] - s);
#pragma unroll
    for (int k = 0; k < 4; k++) {
        if (i0 + k < NBINS) {
            rowptr[i0 + k] = base + p[k];
            cursor[i0 + k] = base + p[k];
        }
    }
}

__global__ void place_kernel(const int* __restrict__ dst, const int* __restrict__ src,
                             const int* __restrict__ etype,
                             int* __restrict__ cursor, int* __restrict__ bsrc) {
    int e = blockIdx.x * blockDim.x + threadIdx.x;
    if (e < NEDGES) {
        int bin = dst[e] * NREL + etype[e];
        int pos = atomicAdd(&cursor[bin], 1);
        bsrc[pos] = src[e];
    }
}

// ---------------- converts ----------------
// Wt2[l][n][r*128+i] = bf16(W[l][r][i][n])

__global__ __launch_bounds__(256) void convert_w(const float* __restrict__ W,
                                                 short* __restrict__ Wt2) {
    int lr = blockIdx.x;
    int l = lr / NREL, r = lr - l * NREL;
    const float* w = W + (size_t)lr * HID * HID;
    short* o = Wt2 + (size_t)l * HID * KTOT;
    int tid = threadIdx.x;
#pragma unroll 4
    for (int i = 0; i < 64; i++) {
        int elem = i * 256 + tid;
        int kk = elem >> 7, n = elem & 127;
        o[(size_t)n * KTOT + r * HID + kk] = f2bf(w[elem]);
    }
}

__global__ __launch_bounds__(256) void convert_emb(const float* __restrict__ E,
                                                   short* __restrict__ Ebf) {
    int gid = blockIdx.x * blockDim.x + threadIdx.x;
    const float* p = E + (size_t)gid * 8;
    float4 v0 = *(const float4*)p;
    float4 v1 = *(const float4*)(p + 4);
    short8 o = {f2bf(v0.x), f2bf(v0.y), f2bf(v0.z), f2bf(v0.w),
                f2bf(v1.x), f2bf(v1.y), f2bf(v1.z), f2bf(v1.w)};
    *(short8*)(Ebf + (size_t)gid * 8) = o;
}

// ---------------- gather: S[bin][0..127] = sum_{e in CSR(bin)} Hbf[src_e] ----------------

__global__ __launch_bounds__(256) void gather_kernel(const short* __restrict__ Hbf,
                                                     const int* __restrict__ bsrc,
                                                     const int* __restrict__ rowptr,
                                                     short* __restrict__ S) {
    int gid = blockIdx.x * blockDim.x + threadIdx.x;
    int bin = gid >> 3;
    if (bin >= NBINS) return;
    int ck  = gid & 7;            // 16 cols each
    int rs = rowptr[bin];
    int re = rowptr[bin + 1];
    float a[16];
#pragma unroll
    for (int i = 0; i < 16; i++) a[i] = 0.f;
    for (int j = rs; j < re; j++) {
        int s = bsrc[j];
        const short* hp = Hbf + (size_t)s * HID + ck * 16;
        short8 v0 = *(const short8*)hp;
        short8 v1 = *(const short8*)(hp + 8);
#pragma unroll
        for (int i = 0; i < 8; i++) a[i]     += bf2f(v0[i]);
#pragma unroll
        for (int i = 0; i < 8; i++) a[i + 8] += bf2f(v1[i]);
    }
    short8 o0 = {f2bf(a[0]),  f2bf(a[1]),  f2bf(a[2]),  f2bf(a[3]),
                 f2bf(a[4]),  f2bf(a[5]),  f2bf(a[6]),  f2bf(a[7])};
    short8 o1 = {f2bf(a[8]),  f2bf(a[9]),  f2bf(a[10]), f2bf(a[11]),
                 f2bf(a[12]), f2bf(a[13]), f2bf(a[14]), f2bf(a[15])};
    short* sp = S + (size_t)bin * HID + ck * 16;
    *(short8*)sp       = o0;
    *(short8*)(sp + 8) = o1;
}

// ---------------- gemm: Hout[d][n] = act( sum_k S[d][k] Wt2[n][k] + sum_r cnt*bias ) ----------------
// 64-row M-tile (782 blocks), K in 18 chunks of 64, register-prefetch pipeline,
// LDS-staged fragments, coalesced bf16 epilogue.

__global__ __launch_bounds__(256) void gemm_kernel(const short* __restrict__ S,
                                                   const short* __restrict__ Wt2l,
                                                   const float* __restrict__ Bias, // [9][128]
                                                   const int* __restrict__ rowptr,
                                                   short* __restrict__ HoutBf,     // !last: bf16+relu
                                                   float* __restrict__ HoutF,      // last: fp32
                                                   int last) {
    __shared__ short lds[GM2 * PITCH + HID * PITCH];   // As | Bs; reused as Et[64][EPITCH]
    __shared__ int   rp_s[GM2 * NREL + 1];
    __shared__ float bias_s[NREL * HID];
    short* As = lds;
    short* Bs = lds + GM2 * PITCH;

    int tid  = threadIdx.x;
    int wave = tid >> 6, lane = tid & 63;
    int row0 = blockIdx.x * GM2;
    int m0   = wave * 16;
    int lm = lane & 15, lq = lane >> 4;

    int rpbase = row0 * NREL;
    for (int i = tid; i <= GM2 * NREL; i += 256) {
        int g = rpbase + i;
        rp_s[i] = rowptr[(g < NBINS) ? g : NBINS];
    }
    for (int i = tid; i < NREL * HID; i += 256) bias_s[i] = Bias[i];

    // per-thread staging slots: 2 A rows + 4 B rows, fixed (row, ck)
    int rowL = tid >> 3;          // 0..31
    int ck   = tid & 7;           // col chunk (8 shorts)
    int ar0 = row0 + rowL;        if (ar0 > NNODES - 1) ar0 = NNODES - 1;
    int ar1 = row0 + 32 + rowL;   if (ar1 > NNODES - 1) ar1 = NNODES - 1;
    const short* pA0 = S + (size_t)ar0 * KTOT + ck * 8;
    const short* pA1 = S + (size_t)ar1 * KTOT + ck * 8;
    const short* pB0 = Wt2l + (size_t)(rowL      ) * KTOT + ck * 8;
    const short* pB1 = Wt2l + (size_t)(rowL + 32 ) * KTOT + ck * 8;
    const short* pB2 = Wt2l + (size_t)(rowL + 64 ) * KTOT + ck * 8;
    const short* pB3 = Wt2l + (size_t)(rowL + 96 ) * KTOT + ck * 8;

    // prefetch chunk 0
    short8 ra0 = *(const short8*)pA0;
    short8 ra1 = *(const short8*)pA1;
    short8 rb0 = *(const short8*)pB0;
    short8 rb1 = *(const short8*)pB1;
    short8 rb2 = *(const short8*)pB2;
    short8 rb3 = *(const short8*)pB3;

    f32x4 acc[8];
#pragma unroll
    for (int nt = 0; nt < 8; nt++) acc[nt] = (f32x4){0.f, 0.f, 0.f, 0.f};

    for (int kc = 0; kc < NCHUNK; kc++) {
        __syncthreads();          // prev chunk's fragment reads done
        *(short8*)&As[ rowL       * PITCH + ck * 8] = ra0;
        *(short8*)&As[(rowL + 32) * PITCH + ck * 8] = ra1;
        *(short8*)&Bs[ rowL       * PITCH + ck * 8] = rb0;
        *(short8*)&Bs[(rowL + 32) * PITCH + ck * 8] = rb1;
        *(short8*)&Bs[(rowL + 64) * PITCH + ck * 8] = rb2;
        *(short8*)&Bs[(rowL + 96) * PITCH + ck * 8] = rb3;
        __syncthreads();
        if (kc + 1 < NCHUNK) {    // issue next chunk's loads; drain at next iter's writes
            int off = (kc + 1) * BK;
            ra0 = *(const short8*)(pA0 + off);
            ra1 = *(const short8*)(pA1 + off);
            rb0 = *(const short8*)(pB0 + off);
            rb1 = *(const short8*)(pB1 + off);
            rb2 = *(const short8*)(pB2 + off);
            rb3 = *(const short8*)(pB3 + off);
        }
#pragma unroll
        for (int ks = 0; ks < 2; ks++) {
            short8 af = *(const short8*)&As[(m0 + lm) * PITCH + ks * 32 + lq * 8];
#pragma unroll
            for (int nt = 0; nt < 8; nt++) {
                short8 bf = *(const short8*)&Bs[(nt * 16 + lm) * PITCH + ks * 32 + lq * 8];
                acc[nt] = __builtin_amdgcn_mfma_f32_16x16x32_bf16(af, bf, acc[nt], 0, 0, 0);
            }
        }
    }
    __syncthreads();   // As/Bs reads done; safe to reuse lds as Et

    // epilogue. C/D layout: col = nt*16+lm, row(in tile) = m0 + lq*4 + reg
    if (!last) {
        short (*Et)[EPITCH] = (short(*)[EPITCH])lds;
#pragma unroll
        for (int reg = 0; reg < 4; reg++) {
            int rl = m0 + lq * 4 + reg;
            float cr[NREL];
#pragma unroll
            for (int r = 0; r < NREL; r++)
                cr[r] = (float)(rp_s[rl * NREL + r + 1] - rp_s[rl * NREL + r]);
#pragma unroll
            for (int nt = 0; nt < 8; nt++) {
                int n = nt * 16 + lm;
                float b = 0.f;
#pragma unroll
                for (int r = 0; r < NREL; r++) b += cr[r] * bias_s[r * HID + n];
                float o = fmaxf(acc[nt][reg] + b, 0.f);
                Et[rl][n] = f2bf(o);
            }
        }
        __syncthreads();
#pragma unroll
        for (int i = 0; i < 4; i++) {
            int p = i * 256 + tid;
            int row = p >> 4, cc = p & 15;
            int d = row0 + row;
            if (d < NNODES)
                *(short8*)(HoutBf + (size_t)d * HID + cc * 8) = *(const short8*)&Et[row][cc * 8];
        }
    } else {
#pragma unroll
        for (int reg = 0; reg < 4; reg++) {
            int rl = m0 + lq * 4 + reg;
            int d  = row0 + rl;
            if (d >= NNODES) continue;
            float cr[NREL];
#pragma unroll
            for (int r = 0; r < NREL; r++)
                cr[r] = (float)(rp_s[rl * NREL + r + 1] - rp_s[rl * NREL + r]);
#pragma unroll
            for (int nt = 0; nt < 8; nt++) {
                int n = nt * 16 + lm;
                float b = 0.f;
#pragma unroll
                for (int r = 0; r < NREL; r++) b += cr[r] * bias_s[r * HID + n];
                HoutF[(size_t)d * HID + n] = acc[nt][reg] + b;
            }
        }
    }
}

// ---------------- driver ----------------

extern "C" void kernel_launch(void* const* d_in, const int* in_sizes, int n_in,
                              void* d_out, int out_size, void* d_ws, size_t ws_size,
                              hipStream_t stream) {
    const int*   edge_index = (const int*)d_in[0];   // [2, NEDGES]: row0=dest, row1=src
    const int*   etype      = (const int*)d_in[1];
    const float* emb        = (const float*)d_in[2];
    const float* W          = (const float*)d_in[3]; // [3,9,128,128]
    const float* Bias       = (const float*)d_in[4]; // [3,9,128]
    float*       out        = (float*)d_out;

    const int* dst  = edge_index;
    const int* srcA = edge_index + NEDGES;

    // ws layout
    short* Ebf = (short*)d_ws;                              // 50000*128 bf16
    short* Hbf = Ebf + (size_t)NNODES * HID;                // 50000*128 bf16
    short* S   = Hbf + (size_t)NNODES * HID;                // 50000*1152 bf16 (115.2 MB)
    short* Wt2 = S + (size_t)NNODES * KTOT;                 // 3*128*1152 bf16
    int*   bsrc     = (int*)(Wt2 + (size_t)NLAYERS * HID * KTOT);
    int*   bins     = bsrc + NEDGES;
    int*   cursor   = bins + NBINS;
    int*   rowptr   = cursor + NBINS;                       // NBINS+1
    int*   blocksum = rowptr + NBINS + 1;
    int*   blockoff = blocksum + NBLK;

    hipMemsetAsync(bins, 0, NBINS * sizeof(int), stream);
    hist2_kernel<<<(NEDGES + 255) / 256, 256, 0, stream>>>(dst, etype, bins);
    scan_pass1<<<NBLK, 256, 0, stream>>>(bins, blocksum);
    scan_pass2<<<1, 512, 0, stream>>>(blocksum, blockoff, rowptr);
    scan_pass3<<<NBLK, 256, 0, stream>>>(bins, blockoff, rowptr, cursor);
    place_kernel<<<(NEDGES + 255) / 256, 256, 0, stream>>>(dst, srcA, etype, cursor, bsrc);
    convert_w<<<NLAYERS * NREL, 256, 0, stream>>>(W, Wt2);
    convert_emb<<<(NNODES * HID / 8) / 256, 256, 0, stream>>>(emb, Ebf);

    const short* Hin = Ebf;
    for (int l = 0; l < NLAYERS; l++) {
        gather_kernel<<<(NBINS * 8 + 255) / 256, 256, 0, stream>>>(Hin, bsrc, rowptr, S);
        const short* Wtl = Wt2 + (size_t)l * HID * KTOT;
        const float* Bl  = Bias + (size_t)l * NREL * HID;
        int last = (l + 1 == NLAYERS);
        gemm_kernel<<<(NNODES + GM2 - 1) / GM2, 256, 0, stream>>>(
            S, Wtl, Bl, rowptr, Hbf, out, last);
        Hin = Hbf;
    }
}